// Round 3
// baseline (8857.011 us; speedup 1.0000x reference)
//
#include <hip/hip_runtime.h>
#include <math.h>

// DCNv2 fused, f16-MFMA, pipelined. Round 3.
// x[8,64,64,256] f32, omw[3,3,256,27], omb[27], wmat[2304,256], bias[256] -> out[8,64,64,256] f32

#define BB 8
#define HH 64
#define WW 64
#define CIN 256
#define FF 256
#define KPTS 9
#define OCH 27
#define MT 32            // pixels per block (half of one (b,oh) row)
#define KSTEPS 72        // 2304 / 32
#define AST 40           // f16 elems per A row (80 B: 16B-aligned, uniform bank coverage)

typedef _Float16 half8  __attribute__((ext_vector_type(8)));
typedef _Float16 half4v __attribute__((ext_vector_type(4)));
typedef float    floatx4 __attribute__((ext_vector_type(4)));

// ---------------- pre-pass: f32 -> f16 swizzled weights ----------------
__global__ __launch_bounds__(256) void convert_wmat(const float* __restrict__ wmat,
                                                    _Float16* __restrict__ wsB) {
    const int k = blockIdx.x;          // 0..2303
    const int n = threadIdx.x;         // 0..255
    wsB[((size_t)(k >> 3) * FF + n) * 8 + (k & 7)] = (_Float16)wmat[k * FF + n];
}

__global__ __launch_bounds__(256) void convert_omw(const float* __restrict__ omw,
                                                   _Float16* __restrict__ wsOM) {
    const int t = blockIdx.x * 256 + threadIdx.x;  // 288*256 = 2304*32
    const int k = t >> 5, n = t & 31;
    const float v = (n < OCH) ? omw[k * OCH + n] : 0.f;
    wsOM[((size_t)(k >> 3) * 32 + n) * 8 + (k & 7)] = (_Float16)v;
}

// ---------------- main fused kernel ----------------
__global__ __launch_bounds__(256) void dcn_mfma(
    const float* __restrict__ x,
    const float* __restrict__ omb,
    const _Float16* __restrict__ wsB,
    const _Float16* __restrict__ wsOM,
    const float* __restrict__ bias,
    float* __restrict__ out)
{
    __shared__ _Float16 Ah[2][MT * AST];      // 5120 B, double-buffered
    __shared__ float    om_s[MT][28];         // 3584 B
    __shared__ floatx4  cwS[MT][KPTS];        // 4608 B
    __shared__ int4     caS[MT][KPTS];        // 4608 B

    const int tid  = threadIdx.x;
    const int w    = tid >> 6;
    const int lane = tid & 63;
    const int q    = lane >> 4;
    const int lr   = lane & 15;

    // batch -> XCD pinning: round-robin dispatch puts block p on XCD p%8;
    // b = p&7 keeps each batch's 4 MB x-slice resident in one XCD's 4 MB L2.
    const int p   = blockIdx.x;
    const int b   = p & 7;
    const int r2  = p >> 3;          // 0..127
    const int oh  = r2 >> 1;
    const int owb = (r2 & 1) * 32;   // ow base of this M-tile
    const int pbase = (b * HH + oh) * WW + owb;

    // staging map: thread -> (pixel row m, channel group of 4)
    const int mrow = tid >> 3;       // 0..31
    const int cg   = tid & 7;        // 0..7

    const half8* wsOM8 = (const half8*)wsOM;
    const half8* wsB8  = (const half8*)wsB;

    // ================= Phase 1: offset/mask conv via MFMA (pipelined) =================
    const int mt1 = w & 1;           // wave's m-tile (16 rows)
    const int nt1 = w >> 1;          // wave's n-tile (16 of 32 padded outputs)
    floatx4 acc1 = {0.f, 0.f, 0.f, 0.f};

    floatx4 cA;
    half8 bPre[2];
    {   // prefetch s=0: kk=0 (ky=0,kx=0), cb=0
        const int iy = oh - 1, ix = owb + mrow - 1;
        floatx4 v = {0.f, 0.f, 0.f, 0.f};
        if (iy >= 0 && ix >= 0 && ix < WW)
            v = *(const floatx4*)(x + ((size_t)((b * HH + iy) * WW + ix) * CIN + cg * 4));
        cA = v;
        bPre[0] = wsOM8[q * 32 + nt1 * 16 + lr];
    }
    for (int s = 0; s < KSTEPS; ++s) {
        const int cur = s & 1;
        half4v hv;
        hv.x = (_Float16)cA.x; hv.y = (_Float16)cA.y;
        hv.z = (_Float16)cA.z; hv.w = (_Float16)cA.w;
        *(half4v*)(&Ah[cur][mrow * AST + cg * 4]) = hv;
        // prefetch s+1 (clamped; redundant last load is harmless)
        {
            const int s2 = (s + 1 < KSTEPS) ? s + 1 : s;
            const int kk = s2 >> 3, cb = (s2 & 7) << 5;
            const int ky = kk / 3, kx = kk % 3;
            const int iy = oh - 1 + ky, ix = owb + mrow - 1 + kx;
            floatx4 v = {0.f, 0.f, 0.f, 0.f};
            if (iy >= 0 && iy < HH && ix >= 0 && ix < WW)
                v = *(const floatx4*)(x + ((size_t)((b * HH + iy) * WW + ix) * CIN + cb + cg * 4));
            cA = v;
            bPre[(s + 1) & 1] = wsOM8[(s2 * 4 + q) * 32 + nt1 * 16 + lr];
        }
        __syncthreads();
        const half8 a = *(const half8*)(&Ah[cur][(mt1 * 16 + lr) * AST + q * 8]);
        acc1 = __builtin_amdgcn_mfma_f32_16x16x32_f16(a, bPre[cur], acc1, 0, 0, 0);
    }
    // write om results
    {
        const int och = nt1 * 16 + lr;
        if (och < OCH) {
            const float ob = omb[och];
            #pragma unroll
            for (int reg = 0; reg < 4; ++reg) {
                const int m = mt1 * 16 + q * 4 + reg;   // C/D: row=(lane>>4)*4+reg
                om_s[m][och] = acc1[reg] + ob;
            }
        }
    }
    __syncthreads();

    // ================= bilinear params =================
    for (int i = tid; i < MT * KPTS; i += 256) {
        const int m = i / KPTS, kk = i % KPTS;
        const int ky = kk / 3, kx = kk % 3;
        const float dy = om_s[m][2 * kk];
        const float dx = om_s[m][2 * kk + 1];
        const float mask = 2.f / (1.f + __expf(-om_s[m][18 + kk]));
        const float py = (float)(oh - 1 + ky) + dy;
        const float px = (float)(owb + m - 1 + kx) + dx;
        const float y0f = floorf(py), x0f = floorf(px);
        const float wy1 = py - y0f, wx1 = px - x0f;
        const float wy0 = 1.f - wy1, wx0 = 1.f - wx1;
        const int y0 = (int)y0f, x0 = (int)x0f;
        const int y1 = y0 + 1, x1 = x0 + 1;
        const bool vy0 = (y0 >= 0) && (y0 < HH);
        const bool vy1 = (y1 >= 0) && (y1 < HH);
        const bool vx0 = (x0 >= 0) && (x0 < WW);
        const bool vx1 = (x1 >= 0) && (x1 < WW);
        const int y0c = min(max(y0, 0), HH - 1), y1c = min(max(y1, 0), HH - 1);
        const int x0c = min(max(x0, 0), WW - 1), x1c = min(max(x1, 0), WW - 1);
        const int rb = b * HH;
        int4 ca;
        ca.x = ((rb + y0c) * WW + x0c) * CIN;
        ca.y = ((rb + y0c) * WW + x1c) * CIN;
        ca.z = ((rb + y1c) * WW + x0c) * CIN;
        ca.w = ((rb + y1c) * WW + x1c) * CIN;
        floatx4 cw;
        cw.x = (vy0 && vx0) ? mask * wy0 * wx0 : 0.f;
        cw.y = (vy0 && vx1) ? mask * wy0 * wx1 : 0.f;
        cw.z = (vy1 && vx0) ? mask * wy1 * wx0 : 0.f;
        cw.w = (vy1 && vx1) ? mask * wy1 * wx1 : 0.f;
        caS[m][kk] = ca;
        cwS[m][kk] = cw;
    }
    __syncthreads();

    // ================= Phase 2: deformable GEMM via MFMA (pipelined) =================
    floatx4 acc[2][4];
    #pragma unroll
    for (int mt = 0; mt < 2; ++mt)
        #pragma unroll
        for (int nt = 0; nt < 4; ++nt)
            acc[mt][nt] = (floatx4){0.f, 0.f, 0.f, 0.f};

    const int n0w = w * 64;
    floatx4 cc0, cc1, cc2, cc3;
    floatx4 cwR[2];
    half8 bP[2][4];
    {   // prefetch s=0
        const int4 ca = caS[mrow][0];
        cwR[0] = cwS[mrow][0];
        const int co = cg * 4;
        cc0 = *(const floatx4*)(x + ca.x + co);
        cc1 = *(const floatx4*)(x + ca.y + co);
        cc2 = *(const floatx4*)(x + ca.z + co);
        cc3 = *(const floatx4*)(x + ca.w + co);
        #pragma unroll
        for (int nt = 0; nt < 4; ++nt)
            bP[0][nt] = wsB8[q * FF + n0w + nt * 16 + lr];
    }
    for (int s = 0; s < KSTEPS; ++s) {
        const int cur = s & 1;
        const floatx4 cw = cwR[cur];
        const floatx4 v = cw.x * cc0 + cw.y * cc1 + cw.z * cc2 + cw.w * cc3;
        half4v hv;
        hv.x = (_Float16)v.x; hv.y = (_Float16)v.y;
        hv.z = (_Float16)v.z; hv.w = (_Float16)v.w;
        *(half4v*)(&Ah[cur][mrow * AST + cg * 4]) = hv;
        // prefetch s+1
        {
            const int s2 = (s + 1 < KSTEPS) ? s + 1 : s;
            const int kk2 = s2 >> 3;
            const int4 ca = caS[mrow][kk2];
            cwR[(s + 1) & 1] = cwS[mrow][kk2];
            const int co = ((s2 & 7) << 5) + cg * 4;
            cc0 = *(const floatx4*)(x + ca.x + co);
            cc1 = *(const floatx4*)(x + ca.y + co);
            cc2 = *(const floatx4*)(x + ca.z + co);
            cc3 = *(const floatx4*)(x + ca.w + co);
            #pragma unroll
            for (int nt = 0; nt < 4; ++nt)
                bP[(s + 1) & 1][nt] = wsB8[(s2 * 4 + q) * FF + n0w + nt * 16 + lr];
        }
        __syncthreads();
        const half8 a0 = *(const half8*)(&Ah[cur][lr * AST + q * 8]);
        const half8 a1 = *(const half8*)(&Ah[cur][(16 + lr) * AST + q * 8]);
        #pragma unroll
        for (int nt = 0; nt < 4; ++nt) {
            acc[0][nt] = __builtin_amdgcn_mfma_f32_16x16x32_f16(a0, bP[cur][nt], acc[0][nt], 0, 0, 0);
            acc[1][nt] = __builtin_amdgcn_mfma_f32_16x16x32_f16(a1, bP[cur][nt], acc[1][nt], 0, 0, 0);
        }
    }

    // ================= epilogue =================
    #pragma unroll
    for (int nt = 0; nt < 4; ++nt) {
        const int f = n0w + nt * 16 + lr;
        const float bv = bias[f];
        #pragma unroll
        for (int mt = 0; mt < 2; ++mt)
            #pragma unroll
            for (int reg = 0; reg < 4; ++reg) {
                const int m = mt * 16 + q * 4 + reg;
                out[(size_t)(pbase + m) * FF + f] = acc[mt][nt][reg] + bv;
            }
    }
}

// ---------------- fp32 fallback (round-1 kernel), used only if ws too small ----------------
#define MTILE 32
#define CHUNK 64
#define NCHUNK (CIN / CHUNK)

__global__ __launch_bounds__(256) void dcn_fused(
    const float* __restrict__ x, const float* __restrict__ omw,
    const float* __restrict__ omb, const float* __restrict__ wmat,
    const float* __restrict__ bias, float* __restrict__ out)
{
    __shared__ float A[CHUNK][MTILE + 1];
    __shared__ float om_s[MTILE][28];
    __shared__ float cw[MTILE][4];
    __shared__ int   ca[MTILE][4];

    const int tid = threadIdx.x;
    const int pbase = blockIdx.x * MTILE;
    const int ccid = tid & 63;
    const int mg2 = tid >> 6;
    const int och = tid & 31;
    const int mg1 = tid >> 5;
    float acc1[4] = {0.f, 0.f, 0.f, 0.f};

    for (int kk = 0; kk < KPTS; ++kk) {
        const int ky = kk / 3, kx = kk % 3;
        for (int ch = 0; ch < NCHUNK; ++ch) {
            const int cbase = ch * CHUNK;
            __syncthreads();
            #pragma unroll
            for (int i = 0; i < 8; ++i) {
                const int m = mg2 * 8 + i;
                const int pp = pbase + m;
                const int bb = pp >> 12, oh = (pp >> 6) & 63, ow = pp & 63;
                const int iy = oh - 1 + ky, ix = ow - 1 + kx;
                float v = 0.f;
                if (iy >= 0 && iy < HH && ix >= 0 && ix < WW)
                    v = x[((bb * HH + iy) * WW + ix) * CIN + cbase + ccid];
                A[ccid][m] = v;
            }
            __syncthreads();
            if (och < OCH) {
                for (int cc = 0; cc < CHUNK; ++cc) {
                    const float bv = omw[((kk * CIN) + cbase + cc) * OCH + och];
                    #pragma unroll
                    for (int i = 0; i < 4; ++i)
                        acc1[i] += A[cc][mg1 * 4 + i] * bv;
                }
            }
        }
    }
    __syncthreads();
    if (och < OCH) {
        const float ob = omb[och];
        #pragma unroll
        for (int i = 0; i < 4; ++i)
            om_s[mg1 * 4 + i][och] = acc1[i] + ob;
    }
    __syncthreads();

    const int f4 = (tid & 63) * 4;
    const int mgc = tid >> 6;
    float acc[8][4];
    #pragma unroll
    for (int j = 0; j < 8; ++j)
        #pragma unroll
        for (int i = 0; i < 4; ++i) acc[j][i] = 0.f;

    for (int kk = 0; kk < KPTS; ++kk) {
        if (tid < MTILE) {
            const int m = tid;
            const int pp = pbase + m;
            const int bb = pp >> 12, oh = (pp >> 6) & 63, ow = pp & 63;
            const int ky = kk / 3, kx = kk % 3;
            const float dy = om_s[m][2 * kk];
            const float dx = om_s[m][2 * kk + 1];
            const float mask = 2.f / (1.f + __expf(-om_s[m][18 + kk]));
            const float py = (float)(oh - 1 + ky) + dy;
            const float px = (float)(ow - 1 + kx) + dx;
            const float y0f = floorf(py), x0f = floorf(px);
            const float wy1 = py - y0f, wx1 = px - x0f;
            const float wy0 = 1.f - wy1, wx0 = 1.f - wx1;
            const int y0 = (int)y0f, x0 = (int)x0f;
            const int y1 = y0 + 1, x1 = x0 + 1;
            const bool vy0 = (y0 >= 0) && (y0 < HH);
            const bool vy1 = (y1 >= 0) && (y1 < HH);
            const bool vx0 = (x0 >= 0) && (x0 < WW);
            const bool vx1 = (x1 >= 0) && (x1 < WW);
            const int y0c = min(max(y0, 0), HH - 1), y1c = min(max(y1, 0), HH - 1);
            const int x0c = min(max(x0, 0), WW - 1), x1c = min(max(x1, 0), WW - 1);
            const int rb = bb * HH;
            ca[m][0] = ((rb + y0c) * WW + x0c) * CIN;
            ca[m][1] = ((rb + y0c) * WW + x1c) * CIN;
            ca[m][2] = ((rb + y1c) * WW + x0c) * CIN;
            ca[m][3] = ((rb + y1c) * WW + x1c) * CIN;
            cw[m][0] = (vy0 && vx0) ? mask * wy0 * wx0 : 0.f;
            cw[m][1] = (vy0 && vx1) ? mask * wy0 * wx1 : 0.f;
            cw[m][2] = (vy1 && vx0) ? mask * wy1 * wx0 : 0.f;
            cw[m][3] = (vy1 && vx1) ? mask * wy1 * wx1 : 0.f;
        }
        for (int ch = 0; ch < NCHUNK; ++ch) {
            const int cbase = ch * CHUNK;
            __syncthreads();
            #pragma unroll
            for (int i = 0; i < 8; ++i) {
                const int m = mg2 * 8 + i;
                const int cidx = cbase + ccid;
                const float v = cw[m][0] * x[ca[m][0] + cidx]
                              + cw[m][1] * x[ca[m][1] + cidx]
                              + cw[m][2] * x[ca[m][2] + cidx]
                              + cw[m][3] * x[ca[m][3] + cidx];
                A[ccid][m] = v;
            }
            __syncthreads();
            const float* brow = wmat + (size_t)(kk * CIN + cbase) * FF + f4;
            for (int cc = 0; cc < CHUNK; ++cc) {
                const float4 bv = *(const float4*)(brow + cc * FF);
                #pragma unroll
                for (int j = 0; j < 8; ++j) {
                    const float a = A[cc][mgc * 8 + j];
                    acc[j][0] += a * bv.x;
                    acc[j][1] += a * bv.y;
                    acc[j][2] += a * bv.z;
                    acc[j][3] += a * bv.w;
                }
            }
        }
    }

    const float4 bb4 = *(const float4*)(bias + f4);
    #pragma unroll
    for (int j = 0; j < 8; ++j) {
        const int m = mgc * 8 + j;
        const int pp = pbase + m;
        float4 o;
        o.x = acc[j][0] + bb4.x;
        o.y = acc[j][1] + bb4.y;
        o.z = acc[j][2] + bb4.z;
        o.w = acc[j][3] + bb4.w;
        *(float4*)(out + (size_t)pp * FF + f4) = o;
    }
}

extern "C" void kernel_launch(void* const* d_in, const int* in_sizes, int n_in,
                              void* d_out, int out_size, void* d_ws, size_t ws_size,
                              hipStream_t stream) {
    const float* x    = (const float*)d_in[0];
    const float* omw  = (const float*)d_in[1];
    const float* omb  = (const float*)d_in[2];
    const float* wmat = (const float*)d_in[3];
    const float* bias = (const float*)d_in[4];
    float* out = (float*)d_out;

    const size_t needB  = (size_t)2304 * FF * sizeof(_Float16);    // 1,179,648 B
    const size_t needOM = (size_t)288 * 32 * 8 * sizeof(_Float16); // 147,456 B

    if (ws_size >= needB + needOM) {
        _Float16* wsB  = (_Float16*)d_ws;
        _Float16* wsOM = (_Float16*)((char*)d_ws + needB);
        convert_wmat<<<2304, 256, 0, stream>>>(wmat, wsB);
        convert_omw<<<288, 256, 0, stream>>>(omw, wsOM);
        dcn_mfma<<<BB * HH * 2, 256, 0, stream>>>(x, omb, wsB, wsOM, bias, out);
    } else {
        const int nblocks = (BB * HH * WW) / MTILE;
        dcn_fused<<<nblocks, 256, 0, stream>>>(x, omw, omb, wmat, bias, out);
    }
}

// Round 4
// 192.034 us; speedup vs baseline: 46.1221x; 46.1221x over previous
//
#include <hip/hip_runtime.h>
#include <math.h>

// DCNv2 fused, f16-MFMA, pipelined with STATIC register sets (round 4).
// x[8,64,64,256] f32, omw[3,3,256,27], omb[27], wmat[2304,256], bias[256] -> out[8,64,64,256] f32

#define BB 8
#define HH 64
#define WW 64
#define CIN 256
#define FF 256
#define KPTS 9
#define OCH 27
#define MT 32            // pixels per block (half of one (b,oh) row)
#define KSTEPS 72        // 2304 / 32
#define AST 40           // f16 elems per A row (80 B)

typedef _Float16 half8  __attribute__((ext_vector_type(8)));
typedef _Float16 half4v __attribute__((ext_vector_type(4)));
typedef float    floatx4 __attribute__((ext_vector_type(4)));

// ---------------- pre-pass: f32 -> f16 swizzled weights ----------------
// wsB[(k/8)*256 + n][8] = wmat[k][n]; one half8 store per thread
__global__ __launch_bounds__(256) void convert_wmat(const float* __restrict__ wmat,
                                                    _Float16* __restrict__ wsB) {
    const int kg = blockIdx.x;         // 0..287 (8 k's each)
    const int n  = threadIdx.x;        // 0..255
    half8 h;
    #pragma unroll
    for (int j = 0; j < 8; ++j)
        h[j] = (_Float16)wmat[(size_t)(kg * 8 + j) * FF + n];
    ((half8*)wsB)[(size_t)kg * FF + n] = h;
}

__global__ __launch_bounds__(256) void convert_omw(const float* __restrict__ omw,
                                                   _Float16* __restrict__ wsOM) {
    const int t = blockIdx.x * 256 + threadIdx.x;  // 288*256 = 2304*32
    const int k = t >> 5, n = t & 31;
    const float v = (n < OCH) ? omw[k * OCH + n] : 0.f;
    wsOM[((size_t)(k >> 3) * 32 + n) * 8 + (k & 7)] = (_Float16)v;
}

// ---------------- main fused kernel ----------------
__global__ __launch_bounds__(256) void dcn_mfma(
    const float* __restrict__ x,
    const float* __restrict__ omb,
    const _Float16* __restrict__ wsB,
    const _Float16* __restrict__ wsOM,
    const float* __restrict__ bias,
    float* __restrict__ out)
{
    __shared__ _Float16 Ah0[MT * AST];        // double buffer, named (no dynamic index)
    __shared__ _Float16 Ah1[MT * AST];
    __shared__ float    om_s[MT][28];
    __shared__ floatx4  cwS[MT][KPTS];
    __shared__ int4     caS[MT][KPTS];

    const int tid  = threadIdx.x;
    const int w    = tid >> 6;
    const int lane = tid & 63;
    const int q    = lane >> 4;
    const int lr   = lane & 15;

    // batch -> XCD pinning: round-robin dispatch puts block p on XCD p%8;
    // b = p&7 keeps each batch's 4 MB x-slice resident in one XCD's L2.
    const int p   = blockIdx.x;
    const int b   = p & 7;
    const int r2  = p >> 3;
    const int oh  = r2 >> 1;
    const int owb = (r2 & 1) * 32;
    const int pbase = (b * HH + oh) * WW + owb;

    const int mrow = tid >> 3;       // 0..31
    const int cg   = tid & 7;        // 0..7

    const half8* wsOM8 = (const half8*)wsOM;
    const half8* wsB8  = (const half8*)wsB;

    // ================= Phase 1: offset/mask conv via MFMA (2x-unrolled pipeline) =================
    const int mt1 = w & 1;
    const int nt1 = w >> 1;
    floatx4 acc1 = {0.f, 0.f, 0.f, 0.f};

    auto pre1 = [&](int s2, floatx4& cA, half8& bPre) {
        const int kk = s2 >> 3, cb = (s2 & 7) << 5;
        const int ky = kk / 3, kx = kk % 3;
        const int iy = oh - 1 + ky, ix = owb + mrow - 1 + kx;
        floatx4 v = {0.f, 0.f, 0.f, 0.f};
        if (iy >= 0 && iy < HH && ix >= 0 && ix < WW)
            v = *(const floatx4*)(x + ((size_t)((b * HH + iy) * WW + ix) * CIN + cb + cg * 4));
        cA = v;
        bPre = wsOM8[(s2 * 4 + q) * 32 + nt1 * 16 + lr];
    };

    floatx4 cA0, cA1;
    half8 bo0, bo1;
    pre1(0, cA0, bo0);
    for (int s = 0; s < KSTEPS; s += 2) {
        {   // even step: stage cA0 -> Ah0, prefetch s+1, compute from Ah0/bo0
            half4v hv;
            hv.x = (_Float16)cA0.x; hv.y = (_Float16)cA0.y;
            hv.z = (_Float16)cA0.z; hv.w = (_Float16)cA0.w;
            *(half4v*)(&Ah0[mrow * AST + cg * 4]) = hv;
            pre1(s + 1, cA1, bo1);
            __syncthreads();
            const half8 a = *(const half8*)(&Ah0[(mt1 * 16 + lr) * AST + q * 8]);
            acc1 = __builtin_amdgcn_mfma_f32_16x16x32_f16(a, bo0, acc1, 0, 0, 0);
        }
        {   // odd step: stage cA1 -> Ah1, prefetch s+2 (clamped), compute from Ah1/bo1
            half4v hv;
            hv.x = (_Float16)cA1.x; hv.y = (_Float16)cA1.y;
            hv.z = (_Float16)cA1.z; hv.w = (_Float16)cA1.w;
            *(half4v*)(&Ah1[mrow * AST + cg * 4]) = hv;
            const int s2 = (s + 2 < KSTEPS) ? s + 2 : KSTEPS - 1;
            pre1(s2, cA0, bo0);
            __syncthreads();
            const half8 a = *(const half8*)(&Ah1[(mt1 * 16 + lr) * AST + q * 8]);
            acc1 = __builtin_amdgcn_mfma_f32_16x16x32_f16(a, bo1, acc1, 0, 0, 0);
        }
    }
    {
        const int och = nt1 * 16 + lr;
        if (och < OCH) {
            const float ob = omb[och];
            #pragma unroll
            for (int reg = 0; reg < 4; ++reg) {
                const int m = mt1 * 16 + q * 4 + reg;   // C/D: row=(lane>>4)*4+reg
                om_s[m][och] = acc1[reg] + ob;
            }
        }
    }
    __syncthreads();

    // ================= bilinear params =================
    for (int i = tid; i < MT * KPTS; i += 256) {
        const int m = i / KPTS, kk = i % KPTS;
        const int ky = kk / 3, kx = kk % 3;
        const float dy = om_s[m][2 * kk];
        const float dx = om_s[m][2 * kk + 1];
        const float mask = 2.f / (1.f + __expf(-om_s[m][18 + kk]));
        const float py = (float)(oh - 1 + ky) + dy;
        const float px = (float)(owb + m - 1 + kx) + dx;
        const float y0f = floorf(py), x0f = floorf(px);
        const float wy1 = py - y0f, wx1 = px - x0f;
        const float wy0 = 1.f - wy1, wx0 = 1.f - wx1;
        const int y0 = (int)y0f, x0 = (int)x0f;
        const int y1 = y0 + 1, x1 = x0 + 1;
        const bool vy0 = (y0 >= 0) && (y0 < HH);
        const bool vy1 = (y1 >= 0) && (y1 < HH);
        const bool vx0 = (x0 >= 0) && (x0 < WW);
        const bool vx1 = (x1 >= 0) && (x1 < WW);
        const int y0c = min(max(y0, 0), HH - 1), y1c = min(max(y1, 0), HH - 1);
        const int x0c = min(max(x0, 0), WW - 1), x1c = min(max(x1, 0), WW - 1);
        const int rb = b * HH;
        int4 ca;
        ca.x = ((rb + y0c) * WW + x0c) * CIN;
        ca.y = ((rb + y0c) * WW + x1c) * CIN;
        ca.z = ((rb + y1c) * WW + x0c) * CIN;
        ca.w = ((rb + y1c) * WW + x1c) * CIN;
        floatx4 cw;
        cw.x = (vy0 && vx0) ? mask * wy0 * wx0 : 0.f;
        cw.y = (vy0 && vx1) ? mask * wy0 * wx1 : 0.f;
        cw.z = (vy1 && vx0) ? mask * wy1 * wx0 : 0.f;
        cw.w = (vy1 && vx1) ? mask * wy1 * wx1 : 0.f;
        caS[m][kk] = ca;
        cwS[m][kk] = cw;
    }
    __syncthreads();

    // ================= Phase 2: deformable GEMM via MFMA (2x-unrolled pipeline) =================
    floatx4 acc[2][4];
    #pragma unroll
    for (int mt = 0; mt < 2; ++mt)
        #pragma unroll
        for (int nt = 0; nt < 4; ++nt)
            acc[mt][nt] = (floatx4){0.f, 0.f, 0.f, 0.f};

    const int n0w = w * 64;

    auto pre2 = [&](int s2, floatx4& c0, floatx4& c1, floatx4& c2, floatx4& c3,
                    floatx4& cw, half8 (&bP)[4]) {
        const int kk2 = s2 >> 3;
        const int4 ca = caS[mrow][kk2];
        cw = cwS[mrow][kk2];
        const int co = ((s2 & 7) << 5) + cg * 4;
        c0 = *(const floatx4*)(x + ca.x + co);
        c1 = *(const floatx4*)(x + ca.y + co);
        c2 = *(const floatx4*)(x + ca.z + co);
        c3 = *(const floatx4*)(x + ca.w + co);
        #pragma unroll
        for (int nt = 0; nt < 4; ++nt)
            bP[nt] = wsB8[(s2 * 4 + q) * FF + n0w + nt * 16 + lr];
    };

    floatx4 ca0, ca1, ca2, ca3, cwa;
    floatx4 cb0, cb1, cb2, cb3, cwb;
    half8 bPa[4], bPb[4];
    pre2(0, ca0, ca1, ca2, ca3, cwa, bPa);

    for (int s = 0; s < KSTEPS; s += 2) {
        {   // even: stage set-a -> Ah0, prefetch s+1 into set-b, compute Ah0 x bPa
            const floatx4 v = cwa.x * ca0 + cwa.y * ca1 + cwa.z * ca2 + cwa.w * ca3;
            half4v hv;
            hv.x = (_Float16)v.x; hv.y = (_Float16)v.y;
            hv.z = (_Float16)v.z; hv.w = (_Float16)v.w;
            *(half4v*)(&Ah0[mrow * AST + cg * 4]) = hv;
            pre2(s + 1, cb0, cb1, cb2, cb3, cwb, bPb);
            __syncthreads();
            const half8 a0 = *(const half8*)(&Ah0[lr * AST + q * 8]);
            const half8 a1 = *(const half8*)(&Ah0[(16 + lr) * AST + q * 8]);
            #pragma unroll
            for (int nt = 0; nt < 4; ++nt) {
                acc[0][nt] = __builtin_amdgcn_mfma_f32_16x16x32_f16(a0, bPa[nt], acc[0][nt], 0, 0, 0);
                acc[1][nt] = __builtin_amdgcn_mfma_f32_16x16x32_f16(a1, bPa[nt], acc[1][nt], 0, 0, 0);
            }
        }
        {   // odd: stage set-b -> Ah1, prefetch s+2 into set-a, compute Ah1 x bPb
            const floatx4 v = cwb.x * cb0 + cwb.y * cb1 + cwb.z * cb2 + cwb.w * cb3;
            half4v hv;
            hv.x = (_Float16)v.x; hv.y = (_Float16)v.y;
            hv.z = (_Float16)v.z; hv.w = (_Float16)v.w;
            *(half4v*)(&Ah1[mrow * AST + cg * 4]) = hv;
            const int s2 = (s + 2 < KSTEPS) ? s + 2 : KSTEPS - 1;
            pre2(s2, ca0, ca1, ca2, ca3, cwa, bPa);
            __syncthreads();
            const half8 a0 = *(const half8*)(&Ah1[lr * AST + q * 8]);
            const half8 a1 = *(const half8*)(&Ah1[(16 + lr) * AST + q * 8]);
            #pragma unroll
            for (int nt = 0; nt < 4; ++nt) {
                acc[0][nt] = __builtin_amdgcn_mfma_f32_16x16x32_f16(a0, bPb[nt], acc[0][nt], 0, 0, 0);
                acc[1][nt] = __builtin_amdgcn_mfma_f32_16x16x32_f16(a1, bPb[nt], acc[1][nt], 0, 0, 0);
            }
        }
    }

    // ================= epilogue =================
    #pragma unroll
    for (int nt = 0; nt < 4; ++nt) {
        const int f = n0w + nt * 16 + lr;
        const float bv = bias[f];
        #pragma unroll
        for (int mt = 0; mt < 2; ++mt)
            #pragma unroll
            for (int reg = 0; reg < 4; ++reg) {
                const int m = mt * 16 + q * 4 + reg;
                out[(size_t)(pbase + m) * FF + f] = acc[mt][nt][reg] + bv;
            }
    }
}

// ---------------- fp32 fallback, used only if ws too small ----------------
#define MTILE 32
#define CHUNK 64
#define NCHUNK (CIN / CHUNK)

__global__ __launch_bounds__(256) void dcn_fused(
    const float* __restrict__ x, const float* __restrict__ omw,
    const float* __restrict__ omb, const float* __restrict__ wmat,
    const float* __restrict__ bias, float* __restrict__ out)
{
    __shared__ float A[CHUNK][MTILE + 1];
    __shared__ float om_s[MTILE][28];
    __shared__ float cw[MTILE][4];
    __shared__ int   ca[MTILE][4];

    const int tid = threadIdx.x;
    const int pbase = blockIdx.x * MTILE;
    const int ccid = tid & 63;
    const int mg2 = tid >> 6;
    const int och = tid & 31;
    const int mg1 = tid >> 5;
    float acc1[4] = {0.f, 0.f, 0.f, 0.f};

    for (int kk = 0; kk < KPTS; ++kk) {
        const int ky = kk / 3, kx = kk % 3;
        for (int ch = 0; ch < NCHUNK; ++ch) {
            const int cbase = ch * CHUNK;
            __syncthreads();
            #pragma unroll
            for (int i = 0; i < 8; ++i) {
                const int m = mg2 * 8 + i;
                const int pp = pbase + m;
                const int bb = pp >> 12, oh = (pp >> 6) & 63, ow = pp & 63;
                const int iy = oh - 1 + ky, ix = ow - 1 + kx;
                float v = 0.f;
                if (iy >= 0 && iy < HH && ix >= 0 && ix < WW)
                    v = x[((bb * HH + iy) * WW + ix) * CIN + cbase + ccid];
                A[ccid][m] = v;
            }
            __syncthreads();
            if (och < OCH) {
                for (int cc = 0; cc < CHUNK; ++cc) {
                    const float bv = omw[((kk * CIN) + cbase + cc) * OCH + och];
                    #pragma unroll
                    for (int i = 0; i < 4; ++i)
                        acc1[i] += A[cc][mg1 * 4 + i] * bv;
                }
            }
        }
    }
    __syncthreads();
    if (och < OCH) {
        const float ob = omb[och];
        #pragma unroll
        for (int i = 0; i < 4; ++i)
            om_s[mg1 * 4 + i][och] = acc1[i] + ob;
    }
    __syncthreads();

    const int f4 = (tid & 63) * 4;
    const int mgc = tid >> 6;
    float acc[8][4];
    #pragma unroll
    for (int j = 0; j < 8; ++j)
        #pragma unroll
        for (int i = 0; i < 4; ++i) acc[j][i] = 0.f;

    for (int kk = 0; kk < KPTS; ++kk) {
        if (tid < MTILE) {
            const int m = tid;
            const int pp = pbase + m;
            const int bb = pp >> 12, oh = (pp >> 6) & 63, ow = pp & 63;
            const int ky = kk / 3, kx = kk % 3;
            const float dy = om_s[m][2 * kk];
            const float dx = om_s[m][2 * kk + 1];
            const float mask = 2.f / (1.f + __expf(-om_s[m][18 + kk]));
            const float py = (float)(oh - 1 + ky) + dy;
            const float px = (float)(ow - 1 + kx) + dx;
            const float y0f = floorf(py), x0f = floorf(px);
            const float wy1 = py - y0f, wx1 = px - x0f;
            const float wy0 = 1.f - wy1, wx0 = 1.f - wx1;
            const int y0 = (int)y0f, x0 = (int)x0f;
            const int y1 = y0 + 1, x1 = x0 + 1;
            const bool vy0 = (y0 >= 0) && (y0 < HH);
            const bool vy1 = (y1 >= 0) && (y1 < HH);
            const bool vx0 = (x0 >= 0) && (x0 < WW);
            const bool vx1 = (x1 >= 0) && (x1 < WW);
            const int y0c = min(max(y0, 0), HH - 1), y1c = min(max(y1, 0), HH - 1);
            const int x0c = min(max(x0, 0), WW - 1), x1c = min(max(x1, 0), WW - 1);
            const int rb = bb * HH;
            ca[m][0] = ((rb + y0c) * WW + x0c) * CIN;
            ca[m][1] = ((rb + y0c) * WW + x1c) * CIN;
            ca[m][2] = ((rb + y1c) * WW + x0c) * CIN;
            ca[m][3] = ((rb + y1c) * WW + x1c) * CIN;
            cw[m][0] = (vy0 && vx0) ? mask * wy0 * wx0 : 0.f;
            cw[m][1] = (vy0 && vx1) ? mask * wy0 * wx1 : 0.f;
            cw[m][2] = (vy1 && vx0) ? mask * wy1 * wx0 : 0.f;
            cw[m][3] = (vy1 && vx1) ? mask * wy1 * wx1 : 0.f;
        }
        for (int ch = 0; ch < NCHUNK; ++ch) {
            const int cbase = ch * CHUNK;
            __syncthreads();
            #pragma unroll
            for (int i = 0; i < 8; ++i) {
                const int m = mg2 * 8 + i;
                const int cidx = cbase + ccid;
                const float v = cw[m][0] * x[ca[m][0] + cidx]
                              + cw[m][1] * x[ca[m][1] + cidx]
                              + cw[m][2] * x[ca[m][2] + cidx]
                              + cw[m][3] * x[ca[m][3] + cidx];
                A[ccid][m] = v;
            }
            __syncthreads();
            const float* brow = wmat + (size_t)(kk * CIN + cbase) * FF + f4;
            for (int cc = 0; cc < CHUNK; ++cc) {
                const float4 bv = *(const float4*)(brow + cc * FF);
                #pragma unroll
                for (int j = 0; j < 8; ++j) {
                    const float a = A[cc][mgc * 8 + j];
                    acc[j][0] += a * bv.x;
                    acc[j][1] += a * bv.y;
                    acc[j][2] += a * bv.z;
                    acc[j][3] += a * bv.w;
                }
            }
        }
    }

    const float4 bb4 = *(const float4*)(bias + f4);
    #pragma unroll
    for (int j = 0; j < 8; ++j) {
        const int m = mgc * 8 + j;
        const int pp = pbase + m;
        float4 o;
        o.x = acc[j][0] + bb4.x;
        o.y = acc[j][1] + bb4.y;
        o.z = acc[j][2] + bb4.z;
        o.w = acc[j][3] + bb4.w;
        *(float4*)(out + (size_t)pp * FF + f4) = o;
    }
}

extern "C" void kernel_launch(void* const* d_in, const int* in_sizes, int n_in,
                              void* d_out, int out_size, void* d_ws, size_t ws_size,
                              hipStream_t stream) {
    const float* x    = (const float*)d_in[0];
    const float* omw  = (const float*)d_in[1];
    const float* omb  = (const float*)d_in[2];
    const float* wmat = (const float*)d_in[3];
    const float* bias = (const float*)d_in[4];
    float* out = (float*)d_out;

    const size_t needB  = (size_t)2304 * FF * sizeof(_Float16);    // 1,179,648 B
    const size_t needOM = (size_t)288 * 32 * 8 * sizeof(_Float16); // 147,456 B

    if (ws_size >= needB + needOM) {
        _Float16* wsB  = (_Float16*)d_ws;
        _Float16* wsOM = (_Float16*)((char*)d_ws + needB);
        convert_wmat<<<288, 256, 0, stream>>>(wmat, wsB);
        convert_omw<<<288, 256, 0, stream>>>(omw, wsOM);
        dcn_mfma<<<BB * HH * 2, 256, 0, stream>>>(x, omb, wsB, wsOM, bias, out);
    } else {
        const int nblocks = (BB * HH * WW) / MTILE;
        dcn_fused<<<nblocks, 256, 0, stream>>>(x, omw, omb, wmat, bias, out);
    }
}

// Round 5
// 170.067 us; speedup vs baseline: 52.0794x; 1.1292x over previous
//
#include <hip/hip_runtime.h>
#include <math.h>

// DCNv2 fused, f16-MFMA, producer-group pipeline, f16-x gather (round 5).
// x[8,64,64,256] f32, omw[3,3,256,27], omb[27], wmat[2304,256], bias[256] -> out[8,64,64,256] f32

#define BB 8
#define HH 64
#define WW 64
#define CIN 256
#define FF 256
#define KPTS 9
#define OCH 27
#define MT 64            // pixels per block = one (b,oh) row
#define KSTEPS 72        // 2304 / 32

typedef _Float16 half8  __attribute__((ext_vector_type(8)));
typedef _Float16 half4v __attribute__((ext_vector_type(4)));
typedef float    floatx4 __attribute__((ext_vector_type(4)));

// A-tile LDS offset (halves). Row stride 32 halves (64 B), XOR swizzle on the
// 8-half k-group: conflict-free b128 writes (m,qc map) AND reads (q,lr map)
// at 8-lane granularity.
__device__ __forceinline__ int aoff(int m, int g) {
    return m * 32 + ((g ^ ((m >> 1) & 3)) << 3);
}

__device__ __forceinline__ half8 splat8(_Float16 v) {
    half8 r = {v, v, v, v, v, v, v, v};
    return r;
}

// ---------------- pre-passes ----------------
__global__ __launch_bounds__(256) void convert_x(const float* __restrict__ x,
                                                 _Float16* __restrict__ xh) {
    const size_t i = ((size_t)blockIdx.x * 256 + threadIdx.x) * 8;
    const floatx4 a = *(const floatx4*)(x + i);
    const floatx4 b = *(const floatx4*)(x + i + 4);
    half8 h;
    h[0] = (_Float16)a.x; h[1] = (_Float16)a.y; h[2] = (_Float16)a.z; h[3] = (_Float16)a.w;
    h[4] = (_Float16)b.x; h[5] = (_Float16)b.y; h[6] = (_Float16)b.z; h[7] = (_Float16)b.w;
    *(half8*)(xh + i) = h;
}

// wsB[(k/8)*256 + n][8] = wmat[k][n]
__global__ __launch_bounds__(256) void convert_wmat(const float* __restrict__ wmat,
                                                    _Float16* __restrict__ wsB) {
    const int kg = blockIdx.x;         // 0..287
    const int n  = threadIdx.x;        // 0..255
    half8 h;
    #pragma unroll
    for (int j = 0; j < 8; ++j)
        h[j] = (_Float16)wmat[(size_t)(kg * 8 + j) * FF + n];
    ((half8*)wsB)[(size_t)kg * FF + n] = h;
}

__global__ __launch_bounds__(256) void convert_omw(const float* __restrict__ omw,
                                                   _Float16* __restrict__ wsOM) {
    const int t = blockIdx.x * 256 + threadIdx.x;  // 288*256 = 2304*32
    const int k = t >> 5, n = t & 31;
    const float v = (n < OCH) ? omw[k * OCH + n] : 0.f;
    wsOM[((size_t)(k >> 3) * 32 + n) * 8 + (k & 7)] = (_Float16)v;
}

// ---------------- main fused kernel ----------------
template <bool F16X>
__global__ __launch_bounds__(512) void dcn_mfma2(
    const float* __restrict__ x,
    const _Float16* __restrict__ xh,
    const float* __restrict__ omb,
    const _Float16* __restrict__ wsB,
    const _Float16* __restrict__ wsOM,
    const float* __restrict__ bias,
    float* __restrict__ out)
{
    __shared__ _Float16 Ah0[MT * 32];     // 4 KB each, double buffer
    __shared__ _Float16 Ah1[MT * 32];
    __shared__ float    om_s[MT][28];     // 7 KB
    __shared__ half4v   cwS[MT][KPTS];    // 4.5 KB  bilinear weights (mask-premult), f16
    __shared__ int4     caS[MT][KPTS];    // 9 KB    clamped corner element bases

    const int tid  = threadIdx.x;
    const int w    = tid >> 6;       // wave 0..7
    const int lane = tid & 63;
    const int q    = lane >> 4;
    const int lr   = lane & 15;
    const int g    = tid >> 8;       // producer group: g stages Ah{g}
    const int st   = tid & 255;
    const int ms   = st >> 2;        // staged row 0..63
    const int qc   = st & 3;         // 8-channel subgroup within K-step

    // batch -> XCD pinning (b = blockIdx%8); block = one (b,oh) row
    const int p  = blockIdx.x;
    const int b  = p & 7;
    const int oh = p >> 3;
    const int pbase = (b * HH + oh) * WW;

    const half8* wsOM8 = (const half8*)wsOM;
    const half8* wsB8  = (const half8*)wsB;

    // ============ Phase 1: offset/mask conv via MFMA ============
    const int mt1 = w & 3;
    const int nt1 = w >> 2;
    floatx4 acc1 = {0.f, 0.f, 0.f, 0.f};

    auto load1 = [&](int sp) -> half8 {
        sp = sp < KSTEPS - 1 ? sp : KSTEPS - 1;
        const int kk = sp >> 3, cb = (sp & 7) << 5;
        const int ky = kk / 3, kx = kk - ky * 3;
        const int iy = oh - 1 + ky, ix = ms - 1 + kx;
        half8 v = {(_Float16)0, (_Float16)0, (_Float16)0, (_Float16)0,
                   (_Float16)0, (_Float16)0, (_Float16)0, (_Float16)0};
        if (iy >= 0 && iy < HH && ix >= 0 && ix < WW) {
            const int idx = ((b * HH + iy) * WW + ix) * CIN + cb + qc * 8;
            if constexpr (F16X) {
                v = *(const half8*)(xh + idx);
            } else {
                const floatx4 lo = *(const floatx4*)(x + idx);
                const floatx4 hi = *(const floatx4*)(x + idx + 4);
                v[0] = (_Float16)lo.x; v[1] = (_Float16)lo.y;
                v[2] = (_Float16)lo.z; v[3] = (_Float16)lo.w;
                v[4] = (_Float16)hi.x; v[5] = (_Float16)hi.y;
                v[6] = (_Float16)hi.z; v[7] = (_Float16)hi.w;
            }
        }
        return v;
    };
    auto loadB1 = [&](int sp) -> half8 {
        sp = sp < KSTEPS - 1 ? sp : KSTEPS - 1;
        return wsOM8[(sp * 4 + q) * 32 + nt1 * 16 + lr];
    };

    half8 vp1;                  // pending staged value (per producer thread)
    half8 bo0, bo1;
    if (g == 0) {
        const half8 v0 = load1(0);
        *(half8*)(Ah0 + aoff(ms, qc)) = v0;
        vp1 = load1(2);
    } else {
        vp1 = load1(1);
    }
    bo0 = loadB1(0);

    for (int s = 0; s < KSTEPS; s += 2) {
        __syncthreads();
        if (g == 1) {
            *(half8*)(Ah1 + aoff(ms, qc)) = vp1;   // data for step s+1
            vp1 = load1(s + 3);
        }
        bo1 = loadB1(s + 1);
        {
            const half8 a = *(const half8*)(Ah0 + aoff(mt1 * 16 + lr, q));
            acc1 = __builtin_amdgcn_mfma_f32_16x16x32_f16(a, bo0, acc1, 0, 0, 0);
        }
        __syncthreads();
        if (g == 0) {
            *(half8*)(Ah0 + aoff(ms, qc)) = vp1;   // data for step s+2
            vp1 = load1(s + 4);
        }
        bo0 = loadB1(s + 2);
        {
            const half8 a = *(const half8*)(Ah1 + aoff(mt1 * 16 + lr, q));
            acc1 = __builtin_amdgcn_mfma_f32_16x16x32_f16(a, bo1, acc1, 0, 0, 0);
        }
    }
    {
        const int och = nt1 * 16 + lr;
        if (och < OCH) {
            const float ob = omb[och];
            #pragma unroll
            for (int reg = 0; reg < 4; ++reg) {
                const int m = mt1 * 16 + q * 4 + reg;   // C/D: row=(lane>>4)*4+reg
                om_s[m][och] = acc1[reg] + ob;
            }
        }
    }
    __syncthreads();

    // ============ bilinear params ============
    for (int i = tid; i < MT * KPTS; i += 512) {
        const int m = i / KPTS, kk = i % KPTS;
        const int ky = kk / 3, kx = kk - ky * 3;
        const float dy = om_s[m][2 * kk];
        const float dx = om_s[m][2 * kk + 1];
        const float mask = 2.f / (1.f + __expf(-om_s[m][18 + kk]));
        const float py = (float)(oh - 1 + ky) + dy;
        const float px = (float)(m - 1 + kx) + dx;
        const float y0f = floorf(py), x0f = floorf(px);
        const float wy1 = py - y0f, wx1 = px - x0f;
        const float wy0 = 1.f - wy1, wx0 = 1.f - wx1;
        const int y0 = (int)y0f, x0 = (int)x0f;
        const int y1 = y0 + 1, x1 = x0 + 1;
        const bool vy0 = (y0 >= 0) && (y0 < HH);
        const bool vy1 = (y1 >= 0) && (y1 < HH);
        const bool vx0 = (x0 >= 0) && (x0 < WW);
        const bool vx1 = (x1 >= 0) && (x1 < WW);
        const int y0c = min(max(y0, 0), HH - 1), y1c = min(max(y1, 0), HH - 1);
        const int x0c = min(max(x0, 0), WW - 1), x1c = min(max(x1, 0), WW - 1);
        const int rb = b * HH;
        int4 ca;
        ca.x = ((rb + y0c) * WW + x0c) * CIN;
        ca.y = ((rb + y0c) * WW + x1c) * CIN;
        ca.z = ((rb + y1c) * WW + x0c) * CIN;
        ca.w = ((rb + y1c) * WW + x1c) * CIN;
        half4v cw;
        cw.x = (_Float16)((vy0 && vx0) ? mask * wy0 * wx0 : 0.f);
        cw.y = (_Float16)((vy0 && vx1) ? mask * wy0 * wx1 : 0.f);
        cw.z = (_Float16)((vy1 && vx0) ? mask * wy1 * wx0 : 0.f);
        cw.w = (_Float16)((vy1 && vx1) ? mask * wy1 * wx1 : 0.f);
        caS[m][kk] = ca;
        cwS[m][kk] = cw;
    }
    __syncthreads();

    // ============ Phase 2: deformable GEMM via MFMA ============
    floatx4 acc[4][2];
    #pragma unroll
    for (int mt = 0; mt < 4; ++mt)
        #pragma unroll
        for (int nt = 0; nt < 2; ++nt)
            acc[mt][nt] = (floatx4){0.f, 0.f, 0.f, 0.f};

    const int n0w = w * 32;   // wave's 32-wide n-slice: wsB read ONCE per block

    // producer pending registers
    half8   pc0, pc1, pc2, pc3;     // f16 corners (F16X path)
    floatx4 fa0, fb0, fa1, fb1, fa2, fb2, fa3, fb3;  // f32 corners (fallback path)
    half4v  pcw;

    auto pre2 = [&](int sp) {
        sp = sp < KSTEPS - 1 ? sp : KSTEPS - 1;
        const int kk = sp >> 3;
        const int co = ((sp & 7) << 5) + qc * 8;
        const int4 ca = caS[ms][kk];
        pcw = cwS[ms][kk];
        if constexpr (F16X) {
            pc0 = *(const half8*)(xh + ca.x + co);
            pc1 = *(const half8*)(xh + ca.y + co);
            pc2 = *(const half8*)(xh + ca.z + co);
            pc3 = *(const half8*)(xh + ca.w + co);
        } else {
            fa0 = *(const floatx4*)(x + ca.x + co); fb0 = *(const floatx4*)(x + ca.x + co + 4);
            fa1 = *(const floatx4*)(x + ca.y + co); fb1 = *(const floatx4*)(x + ca.y + co + 4);
            fa2 = *(const floatx4*)(x + ca.z + co); fb2 = *(const floatx4*)(x + ca.z + co + 4);
            fa3 = *(const floatx4*)(x + ca.w + co); fb3 = *(const floatx4*)(x + ca.w + co + 4);
        }
    };
    auto comb = [&]() -> half8 {
        if constexpr (F16X) {
            const half8 w0 = splat8(pcw.x), w1 = splat8(pcw.y);
            const half8 w2 = splat8(pcw.z), w3 = splat8(pcw.w);
            return pc0 * w0 + pc1 * w1 + pc2 * w2 + pc3 * w3;   // v_pk_fma_f16
        } else {
            const float w0 = (float)pcw.x, w1 = (float)pcw.y;
            const float w2 = (float)pcw.z, w3 = (float)pcw.w;
            const floatx4 lo = w0 * fa0 + w1 * fa1 + w2 * fa2 + w3 * fa3;
            const floatx4 hi = w0 * fb0 + w1 * fb1 + w2 * fb2 + w3 * fb3;
            half8 r;
            r[0] = (_Float16)lo.x; r[1] = (_Float16)lo.y;
            r[2] = (_Float16)lo.z; r[3] = (_Float16)lo.w;
            r[4] = (_Float16)hi.x; r[5] = (_Float16)hi.y;
            r[6] = (_Float16)hi.z; r[7] = (_Float16)hi.w;
            return r;
        }
    };

    half8 bPa[2], bPb[2];
    auto loadB2 = [&](int sp, half8 (&bP)[2]) {
        sp = sp < KSTEPS - 1 ? sp : KSTEPS - 1;
        #pragma unroll
        for (int nt = 0; nt < 2; ++nt)
            bP[nt] = wsB8[(size_t)(sp * 4 + q) * FF + n0w + nt * 16 + lr];
    };

    if (g == 0) {
        pre2(0);
        const half8 v0 = comb();
        *(half8*)(Ah0 + aoff(ms, qc)) = v0;
        pre2(2);
    } else {
        pre2(1);
    }
    loadB2(0, bPa);

    for (int s = 0; s < KSTEPS; s += 2) {
        __syncthreads();
        if (g == 1) {
            const half8 v = comb();                // step s+1 data
            *(half8*)(Ah1 + aoff(ms, qc)) = v;
            pre2(s + 3);
        }
        loadB2(s + 1, bPb);
        {
            half8 afr[4];
            #pragma unroll
            for (int mt = 0; mt < 4; ++mt)
                afr[mt] = *(const half8*)(Ah0 + aoff(mt * 16 + lr, q));
            #pragma unroll
            for (int nt = 0; nt < 2; ++nt)
                #pragma unroll
                for (int mt = 0; mt < 4; ++mt)
                    acc[mt][nt] = __builtin_amdgcn_mfma_f32_16x16x32_f16(afr[mt], bPa[nt], acc[mt][nt], 0, 0, 0);
        }
        __syncthreads();
        if (g == 0) {
            const half8 v = comb();                // step s+2 data
            *(half8*)(Ah0 + aoff(ms, qc)) = v;
            pre2(s + 4);
        }
        loadB2(s + 2, bPa);
        {
            half8 afr[4];
            #pragma unroll
            for (int mt = 0; mt < 4; ++mt)
                afr[mt] = *(const half8*)(Ah1 + aoff(mt * 16 + lr, q));
            #pragma unroll
            for (int nt = 0; nt < 2; ++nt)
                #pragma unroll
                for (int mt = 0; mt < 4; ++mt)
                    acc[mt][nt] = __builtin_amdgcn_mfma_f32_16x16x32_f16(afr[mt], bPb[nt], acc[mt][nt], 0, 0, 0);
        }
    }

    // ============ epilogue ============
    #pragma unroll
    for (int nt = 0; nt < 2; ++nt) {
        const int f = n0w + nt * 16 + lr;
        const float bv = bias[f];
        #pragma unroll
        for (int mt = 0; mt < 4; ++mt)
            #pragma unroll
            for (int reg = 0; reg < 4; ++reg) {
                const int m = mt * 16 + q * 4 + reg;
                out[(size_t)(pbase + m) * FF + f] = acc[mt][nt][reg] + bv;
            }
    }
}

// ---------------- fp32 fallback (known-good round-1 kernel) ----------------
#define MTILE 32
#define CHUNK 64
#define NCHUNK (CIN / CHUNK)

__global__ __launch_bounds__(256) void dcn_fused(
    const float* __restrict__ x, const float* __restrict__ omw,
    const float* __restrict__ omb, const float* __restrict__ wmat,
    const float* __restrict__ bias, float* __restrict__ out)
{
    __shared__ float A[CHUNK][MTILE + 1];
    __shared__ float om_s[MTILE][28];
    __shared__ float cw[MTILE][4];
    __shared__ int   ca[MTILE][4];

    const int tid = threadIdx.x;
    const int pbase = blockIdx.x * MTILE;
    const int ccid = tid & 63;
    const int mg2 = tid >> 6;
    const int och = tid & 31;
    const int mg1 = tid >> 5;
    float acc1[4] = {0.f, 0.f, 0.f, 0.f};

    for (int kk = 0; kk < KPTS; ++kk) {
        const int ky = kk / 3, kx = kk % 3;
        for (int ch = 0; ch < NCHUNK; ++ch) {
            const int cbase = ch * CHUNK;
            __syncthreads();
            #pragma unroll
            for (int i = 0; i < 8; ++i) {
                const int m = mg2 * 8 + i;
                const int pp = pbase + m;
                const int bb = pp >> 12, oh = (pp >> 6) & 63, ow = pp & 63;
                const int iy = oh - 1 + ky, ix = ow - 1 + kx;
                float v = 0.f;
                if (iy >= 0 && iy < HH && ix >= 0 && ix < WW)
                    v = x[((bb * HH + iy) * WW + ix) * CIN + cbase + ccid];
                A[ccid][m] = v;
            }
            __syncthreads();
            if (och < OCH) {
                for (int cc = 0; cc < CHUNK; ++cc) {
                    const float bv = omw[((kk * CIN) + cbase + cc) * OCH + och];
                    #pragma unroll
                    for (int i = 0; i < 4; ++i)
                        acc1[i] += A[cc][mg1 * 4 + i] * bv;
                }
            }
        }
    }
    __syncthreads();
    if (och < OCH) {
        const float ob = omb[och];
        #pragma unroll
        for (int i = 0; i < 4; ++i)
            om_s[mg1 * 4 + i][och] = acc1[i] + ob;
    }
    __syncthreads();

    const int f4 = (tid & 63) * 4;
    const int mgc = tid >> 6;
    float acc[8][4];
    #pragma unroll
    for (int j = 0; j < 8; ++j)
        #pragma unroll
        for (int i = 0; i < 4; ++i) acc[j][i] = 0.f;

    for (int kk = 0; kk < KPTS; ++kk) {
        if (tid < MTILE) {
            const int m = tid;
            const int pp = pbase + m;
            const int bb = pp >> 12, oh = (pp >> 6) & 63, ow = pp & 63;
            const int ky = kk / 3, kx = kk % 3;
            const float dy = om_s[m][2 * kk];
            const float dx = om_s[m][2 * kk + 1];
            const float mask = 2.f / (1.f + __expf(-om_s[m][18 + kk]));
            const float py = (float)(oh - 1 + ky) + dy;
            const float px = (float)(ow - 1 + kx) + dx;
            const float y0f = floorf(py), x0f = floorf(px);
            const float wy1 = py - y0f, wx1 = px - x0f;
            const float wy0 = 1.f - wy1, wx0 = 1.f - wx1;
            const int y0 = (int)y0f, x0 = (int)x0f;
            const int y1 = y0 + 1, x1 = x0 + 1;
            const bool vy0 = (y0 >= 0) && (y0 < HH);
            const bool vy1 = (y1 >= 0) && (y1 < HH);
            const bool vx0 = (x0 >= 0) && (x0 < WW);
            const bool vx1 = (x1 >= 0) && (x1 < WW);
            const int y0c = min(max(y0, 0), HH - 1), y1c = min(max(y1, 0), HH - 1);
            const int x0c = min(max(x0, 0), WW - 1), x1c = min(max(x1, 0), WW - 1);
            const int rb = bb * HH;
            ca[m][0] = ((rb + y0c) * WW + x0c) * CIN;
            ca[m][1] = ((rb + y0c) * WW + x1c) * CIN;
            ca[m][2] = ((rb + y1c) * WW + x0c) * CIN;
            ca[m][3] = ((rb + y1c) * WW + x1c) * CIN;
            cw[m][0] = (vy0 && vx0) ? mask * wy0 * wx0 : 0.f;
            cw[m][1] = (vy0 && vx1) ? mask * wy0 * wx1 : 0.f;
            cw[m][2] = (vy1 && vx0) ? mask * wy1 * wx0 : 0.f;
            cw[m][3] = (vy1 && vx1) ? mask * wy1 * wx1 : 0.f;
        }
        for (int ch = 0; ch < NCHUNK; ++ch) {
            const int cbase = ch * CHUNK;
            __syncthreads();
            #pragma unroll
            for (int i = 0; i < 8; ++i) {
                const int m = mg2 * 8 + i;
                const int cidx = cbase + ccid;
                const float v = cw[m][0] * x[ca[m][0] + cidx]
                              + cw[m][1] * x[ca[m][1] + cidx]
                              + cw[m][2] * x[ca[m][2] + cidx]
                              + cw[m][3] * x[ca[m][3] + cidx];
                A[ccid][m] = v;
            }
            __syncthreads();
            const float* brow = wmat + (size_t)(kk * CIN + cbase) * FF + f4;
            for (int cc = 0; cc < CHUNK; ++cc) {
                const float4 bv = *(const float4*)(brow + cc * FF);
                #pragma unroll
                for (int j = 0; j < 8; ++j) {
                    const float a = A[cc][mgc * 8 + j];
                    acc[j][0] += a * bv.x;
                    acc[j][1] += a * bv.y;
                    acc[j][2] += a * bv.z;
                    acc[j][3] += a * bv.w;
                }
            }
        }
    }

    const float4 bb4 = *(const float4*)(bias + f4);
    #pragma unroll
    for (int j = 0; j < 8; ++j) {
        const int m = mgc * 8 + j;
        const int pp = pbase + m;
        float4 o;
        o.x = acc[j][0] + bb4.x;
        o.y = acc[j][1] + bb4.y;
        o.z = acc[j][2] + bb4.z;
        o.w = acc[j][3] + bb4.w;
        *(float4*)(out + (size_t)pp * FF + f4) = o;
    }
}

extern "C" void kernel_launch(void* const* d_in, const int* in_sizes, int n_in,
                              void* d_out, int out_size, void* d_ws, size_t ws_size,
                              hipStream_t stream) {
    const float* x    = (const float*)d_in[0];
    const float* omw  = (const float*)d_in[1];
    const float* omb  = (const float*)d_in[2];
    const float* wmat = (const float*)d_in[3];
    const float* bias = (const float*)d_in[4];
    float* out = (float*)d_out;

    const size_t needB  = (size_t)2304 * FF * sizeof(_Float16);    // 1,179,648 B
    const size_t needOM = (size_t)288 * 32 * 8 * sizeof(_Float16); // 147,456 B
    const size_t needX  = (size_t)BB * HH * WW * CIN * sizeof(_Float16); // 16,777,216 B

    if (ws_size >= needB + needOM + needX) {
        _Float16* wsB  = (_Float16*)d_ws;
        _Float16* wsOM = (_Float16*)((char*)d_ws + needB);
        _Float16* xh   = (_Float16*)((char*)d_ws + needB + needOM);
        convert_x<<<(BB * HH * WW * CIN) / (256 * 8), 256, 0, stream>>>(x, xh);
        convert_wmat<<<288, 256, 0, stream>>>(wmat, wsB);
        convert_omw<<<288, 256, 0, stream>>>(omw, wsOM);
        dcn_mfma2<true><<<BB * HH, 512, 0, stream>>>(x, xh, omb, wsB, wsOM, bias, out);
    } else if (ws_size >= needB + needOM) {
        _Float16* wsB  = (_Float16*)d_ws;
        _Float16* wsOM = (_Float16*)((char*)d_ws + needB);
        convert_wmat<<<288, 256, 0, stream>>>(wmat, wsB);
        convert_omw<<<288, 256, 0, stream>>>(omw, wsOM);
        dcn_mfma2<false><<<BB * HH, 512, 0, stream>>>(x, nullptr, omb, wsB, wsOM, bias, out);
    } else {
        const int nblocks = (BB * HH * WW) / MTILE;
        dcn_fused<<<nblocks, 256, 0, stream>>>(x, omw, omb, wmat, bias, out);
    }
}

// Round 7
// 163.052 us; speedup vs baseline: 54.3201x; 1.0430x over previous
//
#include <hip/hip_runtime.h>
#include <math.h>

// DCNv2 fused, f16-MFMA, KSTEP=64, fused pre-pass (round 7 = round 6 with XBLK fixed).
// x[8,64,64,256] f32, omw[3,3,256,27], omb[27], wmat[2304,256], bias[256] -> out[8,64,64,256] f32

#define BB 8
#define HH 64
#define WW 64
#define CIN 256
#define FF 256
#define KPTS 9
#define OCH 27
#define MT 64            // pixels per block = one (b,oh) row
#define NS2 36           // K-steps of 64: 2304/64

typedef _Float16 half8  __attribute__((ext_vector_type(8)));
typedef _Float16 half4v __attribute__((ext_vector_type(4)));
typedef float    floatx4 __attribute__((ext_vector_type(4)));

// A-tile LDS offset (halves). Row stride 64 halves (128 B); XOR swizzle of the
// 8-half k-group against (m&7): b128 reads AND writes are <=2-way (free).
__device__ __forceinline__ int aoff(int m, int g) {
    return m * 64 + ((g ^ (m & 7)) << 3);
}

__device__ __forceinline__ half8 splat8(_Float16 v) {
    half8 r = {v, v, v, v, v, v, v, v};
    return r;
}

// ---------------- fused pre-pass: x->f16, wmat->f16 swizzled, omw->f16 swizzled ----------------
// x elems = 8*64*64*256 = 8,388,608; per block 256 thr * 8 elems = 2048 -> 4096 blocks.
#define XBLK 4096
__global__ __launch_bounds__(256) void convert_all(
    const float* __restrict__ x, const float* __restrict__ wmat,
    const float* __restrict__ omw,
    _Float16* __restrict__ xh, _Float16* __restrict__ wsB, _Float16* __restrict__ wsOM)
{
    const int bid = blockIdx.x;
    if (bid < XBLK) {
        if (xh == nullptr) return;
        const size_t i = ((size_t)bid * 256 + threadIdx.x) * 8;
        const floatx4 a = *(const floatx4*)(x + i);
        const floatx4 b = *(const floatx4*)(x + i + 4);
        half8 h;
        h[0] = (_Float16)a.x; h[1] = (_Float16)a.y; h[2] = (_Float16)a.z; h[3] = (_Float16)a.w;
        h[4] = (_Float16)b.x; h[5] = (_Float16)b.y; h[6] = (_Float16)b.z; h[7] = (_Float16)b.w;
        *(half8*)(xh + i) = h;
    } else if (bid < XBLK + 288) {
        // wsB[(k/8)*256 + n][8] = wmat[k][n]
        const int kg = bid - XBLK;       // 0..287
        const int n  = threadIdx.x;      // 0..255
        half8 h;
        #pragma unroll
        for (int j = 0; j < 8; ++j)
            h[j] = (_Float16)wmat[(size_t)(kg * 8 + j) * FF + n];
        ((half8*)wsB)[(size_t)kg * FF + n] = h;
    } else {
        // wsOM[(k/8)*32 + n][8] = omw[k][n] (n>=27 -> 0)
        const int t = (bid - XBLK - 288) * 256 + threadIdx.x;  // 288*256 = 2304*32
        const int k = t >> 5, n = t & 31;
        const float v = (n < OCH) ? omw[k * OCH + n] : 0.f;
        wsOM[((size_t)(k >> 3) * 32 + n) * 8 + (k & 7)] = (_Float16)v;
    }
}

// ---------------- main fused kernel ----------------
template <bool F16X>
__global__ __launch_bounds__(512, 4) void dcn_mfma3(
    const float* __restrict__ x,
    const _Float16* __restrict__ xh,
    const float* __restrict__ omb,
    const _Float16* __restrict__ wsB,
    const _Float16* __restrict__ wsOM,
    const float* __restrict__ bias,
    float* __restrict__ out)
{
    __shared__ _Float16 Ah0[MT * 64];     // 8 KB each, double buffer
    __shared__ _Float16 Ah1[MT * 64];
    __shared__ float    om_s[MT][28];     // 7 KB
    __shared__ half4v   cwS[MT][KPTS];    // 4.5 KB
    __shared__ int4     caS[MT][KPTS];    // 9 KB

    const int tid  = threadIdx.x;
    const int w    = tid >> 6;       // wave 0..7
    const int lane = tid & 63;
    const int q    = lane >> 4;      // k-quad 0..3
    const int lr   = lane & 15;
    const int ms   = tid >> 3;       // staged row 0..63
    const int qc   = tid & 7;        // staged 8-ch group 0..7

    // batch -> XCD pinning (b = blockIdx%8); block = one (b,oh) row
    const int p  = blockIdx.x;
    const int b  = p & 7;
    const int oh = p >> 3;
    const int pbase = (b * HH + oh) * WW;

    const half8* wsOM8 = (const half8*)wsOM;
    const half8* wsB8  = (const half8*)wsB;

    // ============ Phase 1: offset/mask conv via MFMA (KSTEP=64) ============
    const int mt1 = w & 3;
    const int nt1 = w >> 2;
    floatx4 acc1 = {0.f, 0.f, 0.f, 0.f};

    auto load1 = [&](int sp) -> half8 {
        sp = sp < NS2 - 1 ? sp : NS2 - 1;
        const int kk = sp >> 2, cb = (sp & 3) << 6;
        const int ky = kk / 3, kx = kk - ky * 3;
        const int iy = oh - 1 + ky, ix = ms - 1 + kx;
        half8 v = {(_Float16)0, (_Float16)0, (_Float16)0, (_Float16)0,
                   (_Float16)0, (_Float16)0, (_Float16)0, (_Float16)0};
        if (iy >= 0 && iy < HH && ix >= 0 && ix < WW) {
            const int idx = ((b * HH + iy) * WW + ix) * CIN + cb + qc * 8;
            if constexpr (F16X) {
                v = *(const half8*)(xh + idx);
            } else {
                const floatx4 lo = *(const floatx4*)(x + idx);
                const floatx4 hi = *(const floatx4*)(x + idx + 4);
                v[0] = (_Float16)lo.x; v[1] = (_Float16)lo.y;
                v[2] = (_Float16)lo.z; v[3] = (_Float16)lo.w;
                v[4] = (_Float16)hi.x; v[5] = (_Float16)hi.y;
                v[6] = (_Float16)hi.z; v[7] = (_Float16)hi.w;
            }
        }
        return v;
    };
    auto loadB1 = [&](int sp, half8& b0, half8& b1) {
        sp = sp < NS2 - 1 ? sp : NS2 - 1;
        b0 = wsOM8[(sp * 8 + q) * 32 + nt1 * 16 + lr];
        b1 = wsOM8[(sp * 8 + 4 + q) * 32 + nt1 * 16 + lr];
    };

    half8 vp;
    half8 bo00, bo01, bo10, bo11;
    {
        const half8 v0 = load1(0);
        *(half8*)(Ah0 + aoff(ms, qc)) = v0;
        vp = load1(1);
        loadB1(0, bo00, bo01);
    }
    for (int s = 0; s < NS2; s += 2) {
        __syncthreads();
        *(half8*)(Ah1 + aoff(ms, qc)) = vp;       // data for step s+1
        vp = load1(s + 2);
        loadB1(s + 1, bo10, bo11);
        {
            const half8 a0 = *(const half8*)(Ah0 + aoff(mt1 * 16 + lr, q));
            const half8 a1 = *(const half8*)(Ah0 + aoff(mt1 * 16 + lr, 4 + q));
            acc1 = __builtin_amdgcn_mfma_f32_16x16x32_f16(a0, bo00, acc1, 0, 0, 0);
            acc1 = __builtin_amdgcn_mfma_f32_16x16x32_f16(a1, bo01, acc1, 0, 0, 0);
        }
        __syncthreads();
        *(half8*)(Ah0 + aoff(ms, qc)) = vp;       // data for step s+2
        vp = load1(s + 3);
        loadB1(s + 2, bo00, bo01);
        {
            const half8 a0 = *(const half8*)(Ah1 + aoff(mt1 * 16 + lr, q));
            const half8 a1 = *(const half8*)(Ah1 + aoff(mt1 * 16 + lr, 4 + q));
            acc1 = __builtin_amdgcn_mfma_f32_16x16x32_f16(a0, bo10, acc1, 0, 0, 0);
            acc1 = __builtin_amdgcn_mfma_f32_16x16x32_f16(a1, bo11, acc1, 0, 0, 0);
        }
    }
    {
        const int och = nt1 * 16 + lr;
        if (och < OCH) {
            const float ob = omb[och];
            #pragma unroll
            for (int reg = 0; reg < 4; ++reg) {
                const int m = mt1 * 16 + q * 4 + reg;   // C/D: row=(lane>>4)*4+reg
                om_s[m][och] = acc1[reg] + ob;
            }
        }
    }
    __syncthreads();

    // ============ bilinear params ============
    for (int i = tid; i < MT * KPTS; i += 512) {
        const int m = i / KPTS, kk = i % KPTS;
        const int ky = kk / 3, kx = kk - ky * 3;
        const float dy = om_s[m][2 * kk];
        const float dx = om_s[m][2 * kk + 1];
        const float mask = 2.f / (1.f + __expf(-om_s[m][18 + kk]));
        const float py = (float)(oh - 1 + ky) + dy;
        const float px = (float)(m - 1 + kx) + dx;
        const float y0f = floorf(py), x0f = floorf(px);
        const float wy1 = py - y0f, wx1 = px - x0f;
        const float wy0 = 1.f - wy1, wx0 = 1.f - wx1;
        const int y0 = (int)y0f, x0 = (int)x0f;
        const int y1 = y0 + 1, x1 = x0 + 1;
        const bool vy0 = (y0 >= 0) && (y0 < HH);
        const bool vy1 = (y1 >= 0) && (y1 < HH);
        const bool vx0 = (x0 >= 0) && (x0 < WW);
        const bool vx1 = (x1 >= 0) && (x1 < WW);
        const int y0c = min(max(y0, 0), HH - 1), y1c = min(max(y1, 0), HH - 1);
        const int x0c = min(max(x0, 0), WW - 1), x1c = min(max(x1, 0), WW - 1);
        const int rb = b * HH;
        int4 ca;
        ca.x = ((rb + y0c) * WW + x0c) * CIN;
        ca.y = ((rb + y0c) * WW + x1c) * CIN;
        ca.z = ((rb + y1c) * WW + x0c) * CIN;
        ca.w = ((rb + y1c) * WW + x1c) * CIN;
        half4v cw;
        cw.x = (_Float16)((vy0 && vx0) ? mask * wy0 * wx0 : 0.f);
        cw.y = (_Float16)((vy0 && vx1) ? mask * wy0 * wx1 : 0.f);
        cw.z = (_Float16)((vy1 && vx0) ? mask * wy1 * wx0 : 0.f);
        cw.w = (_Float16)((vy1 && vx1) ? mask * wy1 * wx1 : 0.f);
        caS[m][kk] = ca;
        cwS[m][kk] = cw;
    }
    __syncthreads();

    // ============ Phase 2: deformable GEMM via MFMA (KSTEP=64) ============
    floatx4 acc[4][2];
    #pragma unroll
    for (int mt = 0; mt < 4; ++mt)
        #pragma unroll
        for (int nt = 0; nt < 2; ++nt)
            acc[mt][nt] = (floatx4){0.f, 0.f, 0.f, 0.f};

    const int n0w = w * 32;   // wave's 32-wide n-slice: wsB read once per block

    half8   pc0, pc1, pc2, pc3;
    floatx4 fa0, fb0, fa1, fb1, fa2, fb2, fa3, fb3;
    half4v  pcw;

    auto pre2 = [&](int sp) {
        sp = sp < NS2 - 1 ? sp : NS2 - 1;
        const int kk = sp >> 2;
        const int co = ((sp & 3) << 6) + qc * 8;
        const int4 ca = caS[ms][kk];
        pcw = cwS[ms][kk];
        if constexpr (F16X) {
            pc0 = *(const half8*)(xh + ca.x + co);
            pc1 = *(const half8*)(xh + ca.y + co);
            pc2 = *(const half8*)(xh + ca.z + co);
            pc3 = *(const half8*)(xh + ca.w + co);
        } else {
            fa0 = *(const floatx4*)(x + ca.x + co); fb0 = *(const floatx4*)(x + ca.x + co + 4);
            fa1 = *(const floatx4*)(x + ca.y + co); fb1 = *(const floatx4*)(x + ca.y + co + 4);
            fa2 = *(const floatx4*)(x + ca.z + co); fb2 = *(const floatx4*)(x + ca.z + co + 4);
            fa3 = *(const floatx4*)(x + ca.w + co); fb3 = *(const floatx4*)(x + ca.w + co + 4);
        }
    };
    auto comb = [&]() -> half8 {
        if constexpr (F16X) {
            const half8 w0 = splat8(pcw.x), w1 = splat8(pcw.y);
            const half8 w2 = splat8(pcw.z), w3 = splat8(pcw.w);
            return pc0 * w0 + pc1 * w1 + pc2 * w2 + pc3 * w3;   // v_pk_fma_f16
        } else {
            const float w0 = (float)pcw.x, w1 = (float)pcw.y;
            const float w2 = (float)pcw.z, w3 = (float)pcw.w;
            const floatx4 lo = w0 * fa0 + w1 * fa1 + w2 * fa2 + w3 * fa3;
            const floatx4 hi = w0 * fb0 + w1 * fb1 + w2 * fb2 + w3 * fb3;
            half8 r;
            r[0] = (_Float16)lo.x; r[1] = (_Float16)lo.y;
            r[2] = (_Float16)lo.z; r[3] = (_Float16)lo.w;
            r[4] = (_Float16)hi.x; r[5] = (_Float16)hi.y;
            r[6] = (_Float16)hi.z; r[7] = (_Float16)hi.w;
            return r;
        }
    };

    half8 bPa[2][2], bPb[2][2];   // [k-half][n-tile]
    auto loadB2 = [&](int sp, half8 (&bP)[2][2]) {
        sp = sp < NS2 - 1 ? sp : NS2 - 1;
        #pragma unroll
        for (int kh = 0; kh < 2; ++kh)
            #pragma unroll
            for (int nt = 0; nt < 2; ++nt)
                bP[kh][nt] = wsB8[(size_t)(sp * 8 + kh * 4 + q) * FF + n0w + nt * 16 + lr];
    };

    {
        pre2(0);
        const half8 v0 = comb();
        *(half8*)(Ah0 + aoff(ms, qc)) = v0;
        pre2(1);
        loadB2(0, bPa);
    }
    for (int s = 0; s < NS2; s += 2) {
        __syncthreads();
        {
            const half8 v = comb();               // step s+1 data
            *(half8*)(Ah1 + aoff(ms, qc)) = v;
        }
        pre2(s + 2);
        loadB2(s + 1, bPb);
        #pragma unroll
        for (int kh = 0; kh < 2; ++kh) {
            half8 afr[4];
            #pragma unroll
            for (int mt = 0; mt < 4; ++mt)
                afr[mt] = *(const half8*)(Ah0 + aoff(mt * 16 + lr, kh * 4 + q));
            #pragma unroll
            for (int nt = 0; nt < 2; ++nt)
                #pragma unroll
                for (int mt = 0; mt < 4; ++mt)
                    acc[mt][nt] = __builtin_amdgcn_mfma_f32_16x16x32_f16(afr[mt], bPa[kh][nt], acc[mt][nt], 0, 0, 0);
        }
        __syncthreads();
        {
            const half8 v = comb();               // step s+2 data
            *(half8*)(Ah0 + aoff(ms, qc)) = v;
        }
        pre2(s + 3);
        loadB2(s + 2, bPa);
        #pragma unroll
        for (int kh = 0; kh < 2; ++kh) {
            half8 afr[4];
            #pragma unroll
            for (int mt = 0; mt < 4; ++mt)
                afr[mt] = *(const half8*)(Ah1 + aoff(mt * 16 + lr, kh * 4 + q));
            #pragma unroll
            for (int nt = 0; nt < 2; ++nt)
                #pragma unroll
                for (int mt = 0; mt < 4; ++mt)
                    acc[mt][nt] = __builtin_amdgcn_mfma_f32_16x16x32_f16(afr[mt], bPb[kh][nt], acc[mt][nt], 0, 0, 0);
        }
    }

    // ============ epilogue ============
    #pragma unroll
    for (int nt = 0; nt < 2; ++nt) {
        const int f = n0w + nt * 16 + lr;
        const float bv = bias[f];
        #pragma unroll
        for (int mt = 0; mt < 4; ++mt)
            #pragma unroll
            for (int reg = 0; reg < 4; ++reg) {
                const int m = mt * 16 + q * 4 + reg;
                out[(size_t)(pbase + m) * FF + f] = acc[mt][nt][reg] + bv;
            }
    }
}

// ---------------- fp32 fallback (known-good round-1 kernel) ----------------
#define MTILE 32
#define CHUNK 64
#define NCHUNK (CIN / CHUNK)

__global__ __launch_bounds__(256) void dcn_fused(
    const float* __restrict__ x, const float* __restrict__ omw,
    const float* __restrict__ omb, const float* __restrict__ wmat,
    const float* __restrict__ bias, float* __restrict__ out)
{
    __shared__ float A[CHUNK][MTILE + 1];
    __shared__ float om_s[MTILE][28];
    __shared__ float cw[MTILE][4];
    __shared__ int   ca[MTILE][4];

    const int tid = threadIdx.x;
    const int pbase = blockIdx.x * MTILE;
    const int ccid = tid & 63;
    const int mg2 = tid >> 6;
    const int och = tid & 31;
    const int mg1 = tid >> 5;
    float acc1[4] = {0.f, 0.f, 0.f, 0.f};

    for (int kk = 0; kk < KPTS; ++kk) {
        const int ky = kk / 3, kx = kk % 3;
        for (int ch = 0; ch < NCHUNK; ++ch) {
            const int cbase = ch * CHUNK;
            __syncthreads();
            #pragma unroll
            for (int i = 0; i < 8; ++i) {
                const int m = mg2 * 8 + i;
                const int pp = pbase + m;
                const int bb = pp >> 12, oh = (pp >> 6) & 63, ow = pp & 63;
                const int iy = oh - 1 + ky, ix = ow - 1 + kx;
                float v = 0.f;
                if (iy >= 0 && iy < HH && ix >= 0 && ix < WW)
                    v = x[((bb * HH + iy) * WW + ix) * CIN + cbase + ccid];
                A[ccid][m] = v;
            }
            __syncthreads();
            if (och < OCH) {
                for (int cc = 0; cc < CHUNK; ++cc) {
                    const float bv = omw[((kk * CIN) + cbase + cc) * OCH + och];
                    #pragma unroll
                    for (int i = 0; i < 4; ++i)
                        acc1[i] += A[cc][mg1 * 4 + i] * bv;
                }
            }
        }
    }
    __syncthreads();
    if (och < OCH) {
        const float ob = omb[och];
        #pragma unroll
        for (int i = 0; i < 4; ++i)
            om_s[mg1 * 4 + i][och] = acc1[i] + ob;
    }
    __syncthreads();

    const int f4 = (tid & 63) * 4;
    const int mgc = tid >> 6;
    float acc[8][4];
    #pragma unroll
    for (int j = 0; j < 8; ++j)
        #pragma unroll
        for (int i = 0; i < 4; ++i) acc[j][i] = 0.f;

    for (int kk = 0; kk < KPTS; ++kk) {
        if (tid < MTILE) {
            const int m = tid;
            const int pp = pbase + m;
            const int bb = pp >> 12, oh = (pp >> 6) & 63, ow = pp & 63;
            const int ky = kk / 3, kx = kk % 3;
            const float dy = om_s[m][2 * kk];
            const float dx = om_s[m][2 * kk + 1];
            const float mask = 2.f / (1.f + __expf(-om_s[m][18 + kk]));
            const float py = (float)(oh - 1 + ky) + dy;
            const float px = (float)(ow - 1 + kx) + dx;
            const float y0f = floorf(py), x0f = floorf(px);
            const float wy1 = py - y0f, wx1 = px - x0f;
            const float wy0 = 1.f - wy1, wx0 = 1.f - wx1;
            const int y0 = (int)y0f, x0 = (int)x0f;
            const int y1 = y0 + 1, x1 = x0 + 1;
            const bool vy0 = (y0 >= 0) && (y0 < HH);
            const bool vy1 = (y1 >= 0) && (y1 < HH);
            const bool vx0 = (x0 >= 0) && (x0 < WW);
            const bool vx1 = (x1 >= 0) && (x1 < WW);
            const int y0c = min(max(y0, 0), HH - 1), y1c = min(max(y1, 0), HH - 1);
            const int x0c = min(max(x0, 0), WW - 1), x1c = min(max(x1, 0), WW - 1);
            const int rb = bb * HH;
            ca[m][0] = ((rb + y0c) * WW + x0c) * CIN;
            ca[m][1] = ((rb + y0c) * WW + x1c) * CIN;
            ca[m][2] = ((rb + y1c) * WW + x0c) * CIN;
            ca[m][3] = ((rb + y1c) * WW + x1c) * CIN;
            cw[m][0] = (vy0 && vx0) ? mask * wy0 * wx0 : 0.f;
            cw[m][1] = (vy0 && vx1) ? mask * wy0 * wx1 : 0.f;
            cw[m][2] = (vy1 && vx0) ? mask * wy1 * wx0 : 0.f;
            cw[m][3] = (vy1 && vx1) ? mask * wy1 * wx1 : 0.f;
        }
        for (int ch = 0; ch < NCHUNK; ++ch) {
            const int cbase = ch * CHUNK;
            __syncthreads();
            #pragma unroll
            for (int i = 0; i < 8; ++i) {
                const int m = mg2 * 8 + i;
                const int cidx = cbase + ccid;
                const float v = cw[m][0] * x[ca[m][0] + cidx]
                              + cw[m][1] * x[ca[m][1] + cidx]
                              + cw[m][2] * x[ca[m][2] + cidx]
                              + cw[m][3] * x[ca[m][3] + cidx];
                A[ccid][m] = v;
            }
            __syncthreads();
            const float* brow = wmat + (size_t)(kk * CIN + cbase) * FF + f4;
            for (int cc = 0; cc < CHUNK; ++cc) {
                const float4 bv = *(const float4*)(brow + cc * FF);
                #pragma unroll
                for (int j = 0; j < 8; ++j) {
                    const float a = A[cc][mgc * 8 + j];
                    acc[j][0] += a * bv.x;
                    acc[j][1] += a * bv.y;
                    acc[j][2] += a * bv.z;
                    acc[j][3] += a * bv.w;
                }
            }
        }
    }

    const float4 bb4 = *(const float4*)(bias + f4);
    #pragma unroll
    for (int j = 0; j < 8; ++j) {
        const int m = mgc * 8 + j;
        const int pp = pbase + m;
        float4 o;
        o.x = acc[j][0] + bb4.x;
        o.y = acc[j][1] + bb4.y;
        o.z = acc[j][2] + bb4.z;
        o.w = acc[j][3] + bb4.w;
        *(float4*)(out + (size_t)pp * FF + f4) = o;
    }
}

extern "C" void kernel_launch(void* const* d_in, const int* in_sizes, int n_in,
                              void* d_out, int out_size, void* d_ws, size_t ws_size,
                              hipStream_t stream) {
    const float* x    = (const float*)d_in[0];
    const float* omw  = (const float*)d_in[1];
    const float* omb  = (const float*)d_in[2];
    const float* wmat = (const float*)d_in[3];
    const float* bias = (const float*)d_in[4];
    float* out = (float*)d_out;

    const size_t needB  = (size_t)2304 * FF * sizeof(_Float16);    // 1,179,648 B
    const size_t needOM = (size_t)288 * 32 * 8 * sizeof(_Float16); // 147,456 B
    const size_t needX  = (size_t)BB * HH * WW * CIN * sizeof(_Float16); // 16,777,216 B

    if (ws_size >= needB + needOM + needX) {
        _Float16* wsB  = (_Float16*)d_ws;
        _Float16* wsOM = (_Float16*)((char*)d_ws + needB);
        _Float16* xh   = (_Float16*)((char*)d_ws + needB + needOM);
        convert_all<<<XBLK + 288 + 288, 256, 0, stream>>>(x, wmat, omw, xh, wsB, wsOM);
        dcn_mfma3<true><<<BB * HH, 512, 0, stream>>>(x, xh, omb, wsB, wsOM, bias, out);
    } else if (ws_size >= needB + needOM) {
        _Float16* wsB  = (_Float16*)d_ws;
        _Float16* wsOM = (_Float16*)((char*)d_ws + needB);
        convert_all<<<XBLK + 288 + 288, 256, 0, stream>>>(x, wmat, omw, nullptr, wsB, wsOM);
        dcn_mfma3<false><<<BB * HH, 512, 0, stream>>>(x, nullptr, omb, wsB, wsOM, bias, out);
    } else {
        const int nblocks = (BB * HH * WW) / MTILE;
        dcn_fused<<<nblocks, 256, 0, stream>>>(x, omw, omb, wmat, bias, out);
    }
}